// Round 5
// baseline (842.430 us; speedup 1.0000x reference)
//
#include <hip/hip_runtime.h>

typedef __bf16 bf16x8 __attribute__((ext_vector_type(8)));
typedef __bf16 bf16x4 __attribute__((ext_vector_type(4)));
typedef float f32x4 __attribute__((ext_vector_type(4)));

#define MFMA(a,b,c) __builtin_amdgcn_mfma_f32_16x16x32_bf16(a, b, c, 0, 0, 0)

__device__ __forceinline__ float gelu_f(float t) {
    float t2 = t * t;
    float m = t * __builtin_fmaf(-0.07135481627f, t2, -1.5957691216f); // -2z
    float e = __expf(m);
    return t * __builtin_amdgcn_rcpf(1.0f + e);
}

__device__ __forceinline__ bf16x4 shfl_b4(bf16x4 v, int srcLane) {
    union { bf16x4 b; int i[2]; } u; u.b = v;
    u.i[0] = __shfl(u.i[0], srcLane);
    u.i[1] = __shfl(u.i[1], srcLane);
    return u.b;
}
// Build B-fragment bf16x8 for logical cols m*32 + g*8 + e (e=0..7) from packs
// pk[nt] = vals at cols nt*16+4*g'+r (tok=c held fixed). Source lanes c+32*(g&1)(+16).
__device__ __forceinline__ bf16x8 frag_from_packs(const bf16x4* pk, int m, int g, int c) {
    int l_lo = c + 32 * (g & 1);
    int l_hi = l_lo + 16;
    bf16x4 a0 = shfl_b4(pk[2*m],   l_lo);
    bf16x4 a1 = shfl_b4(pk[2*m+1], l_lo);
    bf16x4 b0 = shfl_b4(pk[2*m],   l_hi);
    bf16x4 b1 = shfl_b4(pk[2*m+1], l_hi);
    bool sel = ((g >> 1) & 1);
    bf16x4 lo = sel ? a1 : a0;
    bf16x4 hi = sel ? b1 : b0;
    bf16x8 r;
    #pragma unroll
    for (int i = 0; i < 4; ++i) { r[i] = lo[i]; r[i+4] = hi[i]; }
    return r;
}

// ---------------- kernel 0: weight prep (transpose + bf16, fold qk scale) ----------------
__global__ void prep_weights(const float* __restrict__ wq, const float* __restrict__ wkv,
                             const float* __restrict__ wp, const float* __restrict__ w1,
                             const float* __restrict__ w2, __bf16* __restrict__ ws) {
    int i = blockIdx.x * 256 + threadIdx.x;
    const float scale = 0.17677669529663687f; // 1/sqrt(32)
    if (i < 9216) {                       // wqt[n][k] = wq[k][n]*scale
        int n = i / 96, k = i % 96;
        ws[i] = (__bf16)(wq[k * 96 + n] * scale);
    } else if (i < 27648) {               // wkvt[n][k], n in [0,192)
        int j = i - 9216; int n = j / 96, k = j % 96;
        ws[i] = (__bf16)(wkv[k * 192 + n]);
    } else if (i < 36864) {               // wpt[n][k]
        int j = i - 27648; int n = j / 96, k = j % 96;
        ws[i] = (__bf16)(wp[k * 96 + n]);
    } else if (i < 73728) {               // w1t[n][k], n in [0,384), k in [0,96)
        int j = i - 36864; int n = j / 96, k = j % 96;
        ws[i] = (__bf16)(w1[k * 384 + n]);
    } else if (i < 110592) {              // w2t[n][k], n in [0,96), k in [0,384)
        int j = i - 73728; int n = j / 384, k = j % 384;
        ws[i] = (__bf16)(w2[k * 96 + n]);
    }
}

// ---------------- kernel 1: LN1 + window attention + proj + residual ----------------
#define LDH 104
#define LDV 72

__global__ __launch_bounds__(256, 4) void attn_kernel(
    const float* __restrict__ x, const float* __restrict__ g1v, const float* __restrict__ b1v,
    const float* __restrict__ bq, const float* __restrict__ bkv, const float* __restrict__ bp,
    const __bf16* __restrict__ ws, float* __restrict__ xmid)
{
    const __bf16* wqt  = ws;
    const __bf16* wkvt = ws + 9216;
    const __bf16* wpt  = ws + 27648;

    // per-wave h/proj slice (4 x 16 x 104) | k [64][104] | vt [96][72]  = 40448 B
    __shared__ __align__(16) __bf16 smem[20224];

    const int tid = threadIdx.x;
    const int wv = tid >> 6, lane = tid & 63;
    const int c = lane & 15, g = lane >> 4;

    __bf16* hsl    = smem + wv * (16 * LDH);
    __bf16* k_lds  = smem + 6656;
    __bf16* vt_lds = smem + 13312;

    const int wid = blockIdx.x;
    const int wdI = wid / 576, rem = wid % 576, whI = rem / 24, wwI = rem % 24;
    const int tok = tid >> 2, ltok = tok & 15, cseg = (tid & 3) * 24;
    const int dz = tok >> 4, hy = (tok >> 2) & 3, wx = tok & 3;
    const long gbase = (((long)(wdI * 4 + dz) * 96 + (whI * 4 + hy)) * 96 + (wwI * 4 + wx)) * 96 + cseg;

    const f32x4 fzero = {0.f, 0.f, 0.f, 0.f};

    // ---- phase 0: load x window, LN1 -> per-wave h slice ----
    float xr[24];
    #pragma unroll
    for (int j = 0; j < 6; ++j) {
        float4 v = *reinterpret_cast<const float4*>(x + gbase + j * 4);
        xr[j*4+0] = v.x; xr[j*4+1] = v.y; xr[j*4+2] = v.z; xr[j*4+3] = v.w;
    }
    {
        float s = 0.f;
        #pragma unroll
        for (int j = 0; j < 24; ++j) s += xr[j];
        s += __shfl_xor(s, 1); s += __shfl_xor(s, 2);
        float mu = s * (1.0f / 96.0f);
        float vs = 0.f;
        #pragma unroll
        for (int j = 0; j < 24; ++j) { float d = xr[j] - mu; vs += d * d; }
        vs += __shfl_xor(vs, 1); vs += __shfl_xor(vs, 2);
        float rstd = rsqrtf(vs * (1.0f / 96.0f) + 1e-5f);
        #pragma unroll
        for (int j = 0; j < 6; ++j) {
            f32x4 gv = *reinterpret_cast<const f32x4*>(g1v + cseg + j * 4);
            f32x4 bv = *reinterpret_cast<const f32x4*>(b1v + cseg + j * 4);
            bf16x4 o;
            #pragma unroll
            for (int r = 0; r < 4; ++r) o[r] = (__bf16)((xr[j*4+r] - mu) * rstd * gv[r] + bv[r]);
            *reinterpret_cast<bf16x4*>(&hsl[ltok * LDH + cseg + j*4]) = o;
        }
    }
    __syncthreads();  // bar1

    // ---- phase 1: QKV. own-token-tile B/A fragments from h slice ----
    bf16x8 bH[3];
    #pragma unroll
    for (int kc = 0; kc < 3; ++kc)
        bH[kc] = *reinterpret_cast<const bf16x8*>(&hsl[c * LDH + kc*32 + g*8]);

    bf16x4 qp[6];   // q packs: (qcol = nt*16+4g+r, tok=c)
    {
        f32x4 aq[6];
        #pragma unroll
        for (int nt = 0; nt < 6; ++nt) aq[nt] = fzero;
        #pragma unroll
        for (int nt = 0; nt < 6; ++nt)
            #pragma unroll
            for (int kc = 0; kc < 3; ++kc) {
                bf16x8 aW = *reinterpret_cast<const bf16x8*>(&wqt[(nt*16 + c) * 96 + kc*32 + g*8]);
                aq[nt] = MFMA(aW, bH[kc], aq[nt]);
            }
        #pragma unroll
        for (int nt = 0; nt < 6; ++nt) {
            f32x4 bb = *reinterpret_cast<const f32x4*>(&bq[nt*16 + 4*g]);
            #pragma unroll
            for (int r = 0; r < 4; ++r) qp[nt][r] = (__bf16)(aq[nt][r] + bb[r] * 0.17677669529663687f);
        }
    }
    {   // k for own token tile -> k_lds[tok][kcol]
        f32x4 ak[6];
        #pragma unroll
        for (int nt = 0; nt < 6; ++nt) ak[nt] = fzero;
        #pragma unroll
        for (int nt = 0; nt < 6; ++nt)
            #pragma unroll
            for (int kc = 0; kc < 3; ++kc) {
                bf16x8 aW = *reinterpret_cast<const bf16x8*>(&wkvt[(nt*16 + c) * 96 + kc*32 + g*8]);
                ak[nt] = MFMA(aW, bH[kc], ak[nt]);
            }
        #pragma unroll
        for (int nt = 0; nt < 6; ++nt) {
            f32x4 bb = *reinterpret_cast<const f32x4*>(&bkv[nt*16 + 4*g]);
            bf16x4 o;
            #pragma unroll
            for (int r = 0; r < 4; ++r) o[r] = (__bf16)(ak[nt][r] + bb[r]);
            *reinterpret_cast<bf16x4*>(&k_lds[(wv*16 + c) * LDH + nt*16 + 4*g]) = o;
        }
    }
    {   // v for own token tile -> vt_lds[vcol][tok]
        f32x4 av[6];
        #pragma unroll
        for (int nv = 0; nv < 6; ++nv) av[nv] = fzero;
        #pragma unroll
        for (int nv = 0; nv < 6; ++nv)
            #pragma unroll
            for (int kc = 0; kc < 3; ++kc) {
                bf16x8 bW = *reinterpret_cast<const bf16x8*>(&wkvt[(96 + nv*16 + c) * 96 + kc*32 + g*8]);
                av[nv] = MFMA(bH[kc], bW, av[nv]);
            }
        #pragma unroll
        for (int nv = 0; nv < 6; ++nv) {
            float bias = bkv[96 + nv*16 + c];
            bf16x4 o;
            #pragma unroll
            for (int r = 0; r < 4; ++r) o[r] = (__bf16)(av[nv][r] + bias);
            *reinterpret_cast<bf16x4*>(&vt_lds[(nv*16 + c) * LDV + wv*16 + 4*g]) = o;
        }
    }
    __syncthreads();  // bar2

    // ---- phase 2: attention, wave wv owns query tile wv; all operands reg/shuffle ----
    bf16x4 aop[6];   // attn-out packs (acol = nt*16+4g+r, tok=c)
    #pragma unroll
    for (int h = 0; h < 3; ++h) {
        bf16x8 bQ = frag_from_packs(qp, h, g, c);
        f32x4 sacc[4];
        #pragma unroll
        for (int nt = 0; nt < 4; ++nt) {
            bf16x8 aK = *reinterpret_cast<const bf16x8*>(&k_lds[(nt*16 + c) * LDH + h*32 + g*8]);
            sacc[nt] = fzero;
            sacc[nt] = MFMA(aK, bQ, sacc[nt]);
        }
        float mx = sacc[0][0];
        #pragma unroll
        for (int nt = 0; nt < 4; ++nt)
            #pragma unroll
            for (int r = 0; r < 4; ++r) mx = fmaxf(mx, sacc[nt][r]);
        mx = fmaxf(mx, __shfl_xor(mx, 16));
        mx = fmaxf(mx, __shfl_xor(mx, 32));
        float se = 0.f;
        bf16x4 pp[4];
        float pv[4][4];
        #pragma unroll
        for (int nt = 0; nt < 4; ++nt)
            #pragma unroll
            for (int r = 0; r < 4; ++r) { pv[nt][r] = __expf(sacc[nt][r] - mx); se += pv[nt][r]; }
        se += __shfl_xor(se, 16);
        se += __shfl_xor(se, 32);
        float rsinv = __builtin_amdgcn_rcpf(se);
        #pragma unroll
        for (int nt = 0; nt < 4; ++nt)
            #pragma unroll
            for (int r = 0; r < 4; ++r) pp[nt][r] = (__bf16)pv[nt][r];

        f32x4 oacc[2];
        oacc[0] = fzero; oacc[1] = fzero;
        #pragma unroll
        for (int kc = 0; kc < 2; ++kc) {
            bf16x8 bP = frag_from_packs(pp, kc, g, c);
            #pragma unroll
            for (int n2 = 0; n2 < 2; ++n2) {
                bf16x8 aV = *reinterpret_cast<const bf16x8*>(&vt_lds[(h*32 + n2*16 + c) * LDV + kc*32 + g*8]);
                oacc[n2] = MFMA(aV, bP, oacc[n2]);
            }
        }
        #pragma unroll
        for (int n2 = 0; n2 < 2; ++n2)
            #pragma unroll
            for (int r = 0; r < 4; ++r) aop[2*h + n2][r] = (__bf16)(oacc[n2][r] * rsinv);
    }

    // ---- phase 3: proj from shuffled attn-out fragments; stage in own slice ----
    {
        f32x4 ap[6];
        #pragma unroll
        for (int nt = 0; nt < 6; ++nt) ap[nt] = fzero;
        #pragma unroll
        for (int kc = 0; kc < 3; ++kc) {
            bf16x8 bA = frag_from_packs(aop, kc, g, c);
            #pragma unroll
            for (int nt = 0; nt < 6; ++nt) {
                bf16x8 aW = *reinterpret_cast<const bf16x8*>(&wpt[(nt*16 + c) * 96 + kc*32 + g*8]);
                ap[nt] = MFMA(aW, bA, ap[nt]);
            }
        }
        #pragma unroll
        for (int nt = 0; nt < 6; ++nt) {
            f32x4 bb = *reinterpret_cast<const f32x4*>(&bp[nt*16 + 4*g]);
            bf16x4 o;
            #pragma unroll
            for (int r = 0; r < 4; ++r) o[r] = (__bf16)(ap[nt][r] + bb[r]);
            *reinterpret_cast<bf16x4*>(&hsl[c * LDH + nt*16 + 4*g]) = o;
        }
    }

    // ---- residual: xmid = x + proj (own-wave slice; DS in-order per wave) ----
    #pragma unroll
    for (int j = 0; j < 6; ++j) {
        bf16x4 pr = *reinterpret_cast<const bf16x4*>(&hsl[ltok * LDH + cseg + j*4]);
        float4 v;
        v.x = xr[j*4+0] + (float)pr[0];
        v.y = xr[j*4+1] + (float)pr[1];
        v.z = xr[j*4+2] + (float)pr[2];
        v.w = xr[j*4+3] + (float)pr[3];
        *reinterpret_cast<float4*>(xmid + gbase + j * 4) = v;
    }
}

// ---------------- kernel 2: LN2 + MLP + residual (in place on xmid) ----------------
#define LDU 104
#define LDC 136   // hidden-chunk stride (128 cols + pad)

__global__ __launch_bounds__(256, 5) void mlp_kernel(
    float* __restrict__ xio, const float* __restrict__ g2v, const float* __restrict__ b2v,
    const float* __restrict__ bm1, const float* __restrict__ bm2,
    const __bf16* __restrict__ ws)
{
    const __bf16* w1t = ws + 36864;
    const __bf16* w2t = ws + 73728;

    __shared__ __align__(16) __bf16 u_lds[64 * LDU];     // 13312 B
    __shared__ __align__(16) __bf16 hid[64 * LDC];       // 17408 B  -> total 30720 B

    const int tid = threadIdx.x;
    const int wv = tid >> 6, lane = tid & 63;
    const int c = lane & 15, g = lane >> 4;

    const int tok = tid >> 2, cseg = (tid & 3) * 24;
    const long gaddr = ((long)blockIdx.x * 64 + tok) * 96 + cseg;

    const f32x4 fzero = {0.f, 0.f, 0.f, 0.f};

    // ---- LN2 -> u_lds ----
    {
        float xr[24];
        #pragma unroll
        for (int j = 0; j < 6; ++j) {
            float4 v = *reinterpret_cast<const float4*>(xio + gaddr + j * 4);
            xr[j*4+0] = v.x; xr[j*4+1] = v.y; xr[j*4+2] = v.z; xr[j*4+3] = v.w;
        }
        float s = 0.f;
        #pragma unroll
        for (int j = 0; j < 24; ++j) s += xr[j];
        s += __shfl_xor(s, 1); s += __shfl_xor(s, 2);
        float mu = s * (1.0f / 96.0f);
        float vs = 0.f;
        #pragma unroll
        for (int j = 0; j < 24; ++j) { float d = xr[j] - mu; vs += d * d; }
        vs += __shfl_xor(vs, 1); vs += __shfl_xor(vs, 2);
        float rstd = rsqrtf(vs * (1.0f / 96.0f) + 1e-5f);
        #pragma unroll
        for (int j = 0; j < 6; ++j) {
            f32x4 gv = *reinterpret_cast<const f32x4*>(g2v + cseg + j * 4);
            f32x4 bv = *reinterpret_cast<const f32x4*>(b2v + cseg + j * 4);
            bf16x4 o;
            #pragma unroll
            for (int r = 0; r < 4; ++r) o[r] = (__bf16)((xr[j*4+r] - mu) * rstd * gv[r] + bv[r]);
            *reinterpret_cast<bf16x4*>(&u_lds[tok * LDU + cseg + j*4]) = o;
        }
    }
    __syncthreads();

    // ---- MLP: 3 chunks of 128 hidden ----
    f32x4 accB[6];
    #pragma unroll
    for (int ot = 0; ot < 6; ++ot) accB[ot] = fzero;

    #pragma unroll
    for (int ch = 0; ch < 3; ++ch) {
        // GEMM A: wave -> 2 hidcol tiles x 4 tok tiles. hid[tok][hidcol] (+gelu)
        f32x4 accA[2][4];
        #pragma unroll
        for (int i = 0; i < 2; ++i)
            #pragma unroll
            for (int tt = 0; tt < 4; ++tt) accA[i][tt] = fzero;
        #pragma unroll
        for (int kc = 0; kc < 3; ++kc) {
            bf16x8 bU[4];
            #pragma unroll
            for (int tt = 0; tt < 4; ++tt)
                bU[tt] = *reinterpret_cast<const bf16x8*>(&u_lds[(tt*16 + c) * LDU + kc*32 + g*8]);
            #pragma unroll
            for (int i = 0; i < 2; ++i) {
                bf16x8 aW = *reinterpret_cast<const bf16x8*>(&w1t[(ch*128 + (wv*2+i)*16 + c) * 96 + kc*32 + g*8]);
                #pragma unroll
                for (int tt = 0; tt < 4; ++tt)
                    accA[i][tt] = MFMA(aW, bU[tt], accA[i][tt]);
            }
        }
        #pragma unroll
        for (int i = 0; i < 2; ++i) {
            f32x4 bb = *reinterpret_cast<const f32x4*>(&bm1[ch*128 + (wv*2+i)*16 + 4*g]);
            #pragma unroll
            for (int tt = 0; tt < 4; ++tt) {
                bf16x4 o;
                #pragma unroll
                for (int r = 0; r < 4; ++r) o[r] = (__bf16)gelu_f(accA[i][tt][r] + bb[r]);
                *reinterpret_cast<bf16x4*>(&hid[(tt*16 + c) * LDC + (wv*2+i)*16 + 4*g]) = o;
            }
        }
        __syncthreads();  // hid ready

        // GEMM B: accB += w2 chunk rows x own-token hid fragments. K=128
        #pragma unroll
        for (int kc = 0; kc < 4; ++kc) {
            bf16x8 bHd = *reinterpret_cast<const bf16x8*>(&hid[(wv*16 + c) * LDC + kc*32 + g*8]);
            #pragma unroll
            for (int ot = 0; ot < 6; ++ot) {
                bf16x8 aW = *reinterpret_cast<const bf16x8*>(&w2t[(ot*16 + c) * 384 + ch*128 + kc*32 + g*8]);
                accB[ot] = MFMA(aW, bHd, accB[ot]);
            }
        }
        if (ch < 2) __syncthreads();  // protect hid overwrite
    }

    // ---- epilogue -> u_lds own rows (intra-wave), residual with re-read x ----
    #pragma unroll
    for (int ot = 0; ot < 6; ++ot) {
        f32x4 bb = *reinterpret_cast<const f32x4*>(&bm2[ot*16 + 4*g]);
        bf16x4 o;
        #pragma unroll
        for (int r = 0; r < 4; ++r) o[r] = (__bf16)(accB[ot][r] + bb[r]);
        *reinterpret_cast<bf16x4*>(&u_lds[(wv*16 + c) * LDU + ot*16 + 4*g]) = o;
    }
    #pragma unroll
    for (int j = 0; j < 6; ++j) {
        float4 xv = *reinterpret_cast<const float4*>(xio + gaddr + j * 4);
        bf16x4 mo = *reinterpret_cast<const bf16x4*>(&u_lds[tok * LDU + cseg + j*4]);
        float4 v;
        v.x = xv.x + (float)mo[0];
        v.y = xv.y + (float)mo[1];
        v.z = xv.z + (float)mo[2];
        v.w = xv.w + (float)mo[3];
        *reinterpret_cast<float4*>(xio + gaddr + j * 4) = v;
    }
}

extern "C" void kernel_launch(void* const* d_in, const int* in_sizes, int n_in,
                              void* d_out, int out_size, void* d_ws, size_t ws_size,
                              hipStream_t stream) {
    (void)in_sizes; (void)n_in; (void)out_size; (void)ws_size;
    const float* x   = (const float*)d_in[0];
    const float* g1  = (const float*)d_in[1];
    const float* b1  = (const float*)d_in[2];
    const float* wq  = (const float*)d_in[3];
    const float* bq  = (const float*)d_in[4];
    const float* wkv = (const float*)d_in[5];
    const float* bkv = (const float*)d_in[6];
    const float* wp  = (const float*)d_in[7];
    const float* bp  = (const float*)d_in[8];
    const float* g2  = (const float*)d_in[9];
    const float* b2  = (const float*)d_in[10];
    const float* w1  = (const float*)d_in[11];
    const float* bm1 = (const float*)d_in[12];
    const float* w2  = (const float*)d_in[13];
    const float* bm2 = (const float*)d_in[14];
    float* out = (float*)d_out;
    __bf16* ws = (__bf16*)d_ws;

    prep_weights<<<432, 256, 0, stream>>>(wq, wkv, wp, w1, w2, ws);
    attn_kernel<<<9216, 256, 0, stream>>>(x, g1, b1, bq, bkv, bp, ws, out);
    mlp_kernel<<<9216, 256, 0, stream>>>(out, g2, b2, bm1, bm2, ws);
}

// Round 6
// 575.031 us; speedup vs baseline: 1.4650x; 1.4650x over previous
//
#include <hip/hip_runtime.h>

typedef __bf16 bf16x8 __attribute__((ext_vector_type(8)));
typedef __bf16 bf16x4 __attribute__((ext_vector_type(4)));
typedef float f32x4 __attribute__((ext_vector_type(4)));

#define MFMA(a,b,c) __builtin_amdgcn_mfma_f32_16x16x32_bf16(a, b, c, 0, 0, 0)

__device__ __forceinline__ float gelu_f(float t) {
    float t2 = t * t;
    float m = t * __builtin_fmaf(-0.07135481627f, t2, -1.5957691216f); // -2z
    float e = __expf(m);
    return t * __builtin_amdgcn_rcpf(1.0f + e);
}

// ---------------- kernel 0: weight prep (transpose + bf16, fold qk scale) ----------------
__global__ void prep_weights(const float* __restrict__ wq, const float* __restrict__ wkv,
                             const float* __restrict__ wp, const float* __restrict__ w1,
                             const float* __restrict__ w2, __bf16* __restrict__ ws) {
    int i = blockIdx.x * 256 + threadIdx.x;
    const float scale = 0.17677669529663687f; // 1/sqrt(32)
    if (i < 9216) {                       // wqt[n][k] = wq[k][n]*scale
        int n = i / 96, k = i % 96;
        ws[i] = (__bf16)(wq[k * 96 + n] * scale);
    } else if (i < 27648) {               // wkvt[n][k], n in [0,192)
        int j = i - 9216; int n = j / 96, k = j % 96;
        ws[i] = (__bf16)(wkv[k * 192 + n]);
    } else if (i < 36864) {               // wpt[n][k]
        int j = i - 27648; int n = j / 96, k = j % 96;
        ws[i] = (__bf16)(wp[k * 96 + n]);
    } else if (i < 73728) {               // w1t[n][k], n in [0,384), k in [0,96)
        int j = i - 36864; int n = j / 96, k = j % 96;
        ws[i] = (__bf16)(w1[k * 384 + n]);
    } else if (i < 110592) {              // w2t[n][k], n in [0,96), k in [0,384)
        int j = i - 73728; int n = j / 384, k = j % 384;
        ws[i] = (__bf16)(w2[k * 96 + n]);
    }
}

// ---------------- kernel 1: LN1 + window attention + proj + residual ----------------
#define LDH 104   // 96 + pad
#define LDV 72

#define AOFF_H   0
#define AOFF_Q   6656
#define AOFF_K   13312
#define AOFF_VT  19968
#define AOFF_P   26880
#define ASMEM    31488      // bf16 elems -> 62976 B

__global__ __launch_bounds__(256, 2) void attn_kernel(
    const float* __restrict__ x, const float* __restrict__ g1v, const float* __restrict__ b1v,
    const float* __restrict__ bq, const float* __restrict__ bkv, const float* __restrict__ bp,
    const __bf16* __restrict__ ws, float* __restrict__ xmid)
{
    const __bf16* wqt  = ws;
    const __bf16* wkvt = ws + 9216;
    const __bf16* wpt  = ws + 27648;

    __shared__ __align__(16) __bf16 smem[ASMEM];
    __bf16* h_lds  = smem + AOFF_H;   // LN1 out -> attn out
    __bf16* q_lds  = smem + AOFF_Q;   // q -> proj out
    __bf16* k_lds  = smem + AOFF_K;
    __bf16* vt_lds = smem + AOFF_VT;  // v transposed [vcol][tok]
    __bf16* p_lds  = smem + AOFF_P;   // per-wave P scratch

    const int tid = threadIdx.x;
    const int wv = tid >> 6, lane = tid & 63;
    const int c = lane & 15, g = lane >> 4;

    const int wid = blockIdx.x;
    const int wdI = wid / 576, rem = wid % 576, whI = rem / 24, wwI = rem % 24;
    const int tok = tid >> 2, cseg = (tid & 3) * 24;
    const int dz = tok >> 4, hy = (tok >> 2) & 3, wx = tok & 3;
    const long gbase = (((long)(wdI * 4 + dz) * 96 + (whI * 4 + hy)) * 96 + (wwI * 4 + wx)) * 96 + cseg;

    const f32x4 fzero = {0.f, 0.f, 0.f, 0.f};

    // ---- phase 0: load x window, LN1 -> h_lds ----
    float xr[24];
    #pragma unroll
    for (int j = 0; j < 6; ++j) {
        float4 v = *reinterpret_cast<const float4*>(x + gbase + j * 4);
        xr[j*4+0] = v.x; xr[j*4+1] = v.y; xr[j*4+2] = v.z; xr[j*4+3] = v.w;
    }
    {
        float s = 0.f;
        #pragma unroll
        for (int j = 0; j < 24; ++j) s += xr[j];
        s += __shfl_xor(s, 1); s += __shfl_xor(s, 2);
        float mu = s * (1.0f / 96.0f);
        float vs = 0.f;
        #pragma unroll
        for (int j = 0; j < 24; ++j) { float d = xr[j] - mu; vs += d * d; }
        vs += __shfl_xor(vs, 1); vs += __shfl_xor(vs, 2);
        float rstd = rsqrtf(vs * (1.0f / 96.0f) + 1e-5f);
        #pragma unroll
        for (int j = 0; j < 6; ++j) {
            f32x4 gv = *reinterpret_cast<const f32x4*>(g1v + cseg + j * 4);
            f32x4 bv = *reinterpret_cast<const f32x4*>(b1v + cseg + j * 4);
            bf16x4 o;
            #pragma unroll
            for (int r = 0; r < 4; ++r) o[r] = (__bf16)((xr[j*4+r] - mu) * rstd * gv[r] + bv[r]);
            *reinterpret_cast<bf16x4*>(&h_lds[tok * LDH + cseg + j*4]) = o;
        }
    }
    __syncthreads();  // bar1

    // ---- phase 1: QKV projections ----
    // q (all waves, swapped: A=wq rows, B=own token-tile) -> q_lds[tok][qcol]
    {
        bf16x8 bH[3];
        #pragma unroll
        for (int kc = 0; kc < 3; ++kc)
            bH[kc] = *reinterpret_cast<const bf16x8*>(&h_lds[(wv*16 + c) * LDH + kc*32 + g*8]);
        f32x4 aq[6];
        #pragma unroll
        for (int nt = 0; nt < 6; ++nt) aq[nt] = fzero;
        #pragma unroll
        for (int nt = 0; nt < 6; ++nt)
            #pragma unroll
            for (int kc = 0; kc < 3; ++kc) {
                bf16x8 aW = *reinterpret_cast<const bf16x8*>(&wqt[(nt*16 + c) * 96 + kc*32 + g*8]);
                aq[nt] = MFMA(aW, bH[kc], aq[nt]);
            }
        #pragma unroll
        for (int nt = 0; nt < 6; ++nt) {
            f32x4 bb = *reinterpret_cast<const f32x4*>(&bq[nt*16 + 4*g]);
            bf16x4 o;
            #pragma unroll
            for (int r = 0; r < 4; ++r) o[r] = (__bf16)(aq[nt][r] + bb[r] * 0.17677669529663687f);
            *reinterpret_cast<bf16x4*>(&q_lds[(wv*16 + c) * LDH + nt*16 + 4*g]) = o;
        }
    }
    if (wv < 2) {
        // k (swapped): waves 0,1 cover token-tiles {2wv, 2wv+1} -> k_lds[tok][kcol]
        #pragma unroll
        for (int t2 = 0; t2 < 2; ++t2) {
            int tt = wv*2 + t2;
            bf16x8 bH[3];
            #pragma unroll
            for (int kc = 0; kc < 3; ++kc)
                bH[kc] = *reinterpret_cast<const bf16x8*>(&h_lds[(tt*16 + c) * LDH + kc*32 + g*8]);
            f32x4 ak[6];
            #pragma unroll
            for (int nt = 0; nt < 6; ++nt) ak[nt] = fzero;
            #pragma unroll
            for (int nt = 0; nt < 6; ++nt)
                #pragma unroll
                for (int kc = 0; kc < 3; ++kc) {
                    bf16x8 aW = *reinterpret_cast<const bf16x8*>(&wkvt[(nt*16 + c) * 96 + kc*32 + g*8]);
                    ak[nt] = MFMA(aW, bH[kc], ak[nt]);
                }
            #pragma unroll
            for (int nt = 0; nt < 6; ++nt) {
                f32x4 bb = *reinterpret_cast<const f32x4*>(&bkv[nt*16 + 4*g]);
                bf16x4 o;
                #pragma unroll
                for (int r = 0; r < 4; ++r) o[r] = (__bf16)(ak[nt][r] + bb[r]);
                *reinterpret_cast<bf16x4*>(&k_lds[(tt*16 + c) * LDH + nt*16 + 4*g]) = o;
            }
        }
    } else {
        // v (unswapped: A=token rows, B=wkv v-rows) -> vt_lds[vcol][tok]
        f32x4 av[4][3];
        #pragma unroll
        for (int m = 0; m < 4; ++m)
            #pragma unroll
            for (int nl = 0; nl < 3; ++nl) av[m][nl] = fzero;
        #pragma unroll
        for (int kc = 0; kc < 3; ++kc) {
            bf16x8 aH[4];
            #pragma unroll
            for (int m = 0; m < 4; ++m)
                aH[m] = *reinterpret_cast<const bf16x8*>(&h_lds[(m*16 + c) * LDH + kc*32 + g*8]);
            #pragma unroll
            for (int nl = 0; nl < 3; ++nl) {
                int nv = (wv - 2) * 3 + nl;
                bf16x8 bW = *reinterpret_cast<const bf16x8*>(&wkvt[(96 + nv*16 + c) * 96 + kc*32 + g*8]);
                #pragma unroll
                for (int m = 0; m < 4; ++m)
                    av[m][nl] = MFMA(aH[m], bW, av[m][nl]);
            }
        }
        #pragma unroll
        for (int nl = 0; nl < 3; ++nl) {
            int nv = (wv - 2) * 3 + nl;
            float bias = bkv[96 + nv*16 + c];
            #pragma unroll
            for (int m = 0; m < 4; ++m) {
                bf16x4 o;
                #pragma unroll
                for (int r = 0; r < 4; ++r) o[r] = (__bf16)(av[m][nl][r] + bias);
                *reinterpret_cast<bf16x4*>(&vt_lds[(nv*16 + c) * LDV + m*16 + 4*g]) = o;
            }
        }
    }
    __syncthreads();  // bar2

    // ---- phase 2: attention (wave wv owns query tile wv) ----
    __bf16* p_w = p_lds + wv * (16 * LDV);
    #pragma unroll
    for (int h = 0; h < 3; ++h) {
        // QK^T swapped: A=key tiles, B=own q tile. sacc[nt][r] = S[key=nt*16+4g+r][qtok=c]
        f32x4 sacc[4];
        bf16x8 bQ = *reinterpret_cast<const bf16x8*>(&q_lds[(wv*16 + c) * LDH + h*32 + g*8]);
        #pragma unroll
        for (int nt = 0; nt < 4; ++nt) {
            bf16x8 aK = *reinterpret_cast<const bf16x8*>(&k_lds[(nt*16 + c) * LDH + h*32 + g*8]);
            sacc[nt] = fzero;
            sacc[nt] = MFMA(aK, bQ, sacc[nt]);
        }
        // softmax over keys (16 in-lane + cross-g shfls)
        float mx = sacc[0][0];
        #pragma unroll
        for (int nt = 0; nt < 4; ++nt)
            #pragma unroll
            for (int r = 0; r < 4; ++r) mx = fmaxf(mx, sacc[nt][r]);
        mx = fmaxf(mx, __shfl_xor(mx, 16));
        mx = fmaxf(mx, __shfl_xor(mx, 32));
        float p[4][4]; float se = 0.f;
        #pragma unroll
        for (int nt = 0; nt < 4; ++nt)
            #pragma unroll
            for (int r = 0; r < 4; ++r) { p[nt][r] = __expf(sacc[nt][r] - mx); se += p[nt][r]; }
        se += __shfl_xor(se, 16);
        se += __shfl_xor(se, 32);
        float rsinv = __builtin_amdgcn_rcpf(se);
        #pragma unroll
        for (int nt = 0; nt < 4; ++nt) {
            bf16x4 o;
            #pragma unroll
            for (int r = 0; r < 4; ++r) o[r] = (__bf16)p[nt][r];
            *reinterpret_cast<bf16x4*>(&p_w[c * LDV + nt*16 + 4*g]) = o;
        }
        // PV swapped: A=vt rows (vcols), B=p rows (qtoks). out (vcol, qtok=c)
        f32x4 oacc[2];
        oacc[0] = fzero;
        oacc[1] = fzero;
        #pragma unroll
        for (int kc = 0; kc < 2; ++kc) {
            bf16x8 bP = *reinterpret_cast<const bf16x8*>(&p_w[c * LDV + kc*32 + g*8]);
            #pragma unroll
            for (int n2 = 0; n2 < 2; ++n2) {
                bf16x8 aV = *reinterpret_cast<const bf16x8*>(&vt_lds[(h*32 + n2*16 + c) * LDV + kc*32 + g*8]);
                oacc[n2] = MFMA(aV, bP, oacc[n2]);
            }
        }
        #pragma unroll
        for (int n2 = 0; n2 < 2; ++n2) {
            bf16x4 o;
            #pragma unroll
            for (int r = 0; r < 4; ++r) o[r] = (__bf16)(oacc[n2][r] * rsinv);
            *reinterpret_cast<bf16x4*>(&h_lds[(wv*16 + c) * LDH + h*32 + n2*16 + 4*g]) = o;
        }
    }

    // ---- phase 3: proj (swapped; own-wave rows only, no barrier needed) ----
    {
        bf16x8 bA[3];
        #pragma unroll
        for (int kc = 0; kc < 3; ++kc)
            bA[kc] = *reinterpret_cast<const bf16x8*>(&h_lds[(wv*16 + c) * LDH + kc*32 + g*8]);
        f32x4 ap[6];
        #pragma unroll
        for (int nt = 0; nt < 6; ++nt) ap[nt] = fzero;
        #pragma unroll
        for (int nt = 0; nt < 6; ++nt)
            #pragma unroll
            for (int kc = 0; kc < 3; ++kc) {
                bf16x8 aW = *reinterpret_cast<const bf16x8*>(&wpt[(nt*16 + c) * 96 + kc*32 + g*8]);
                ap[nt] = MFMA(aW, bA[kc], ap[nt]);
            }
        #pragma unroll
        for (int nt = 0; nt < 6; ++nt) {
            f32x4 bb = *reinterpret_cast<const f32x4*>(&bp[nt*16 + 4*g]);
            bf16x4 o;
            #pragma unroll
            for (int r = 0; r < 4; ++r) o[r] = (__bf16)(ap[nt][r] + bb[r]);
            *reinterpret_cast<bf16x4*>(&q_lds[(wv*16 + c) * LDH + nt*16 + 4*g]) = o;
        }
    }

    // ---- phase 4: residual store (tok rows are own-wave rows: tid>>2 in [wv*16, wv*16+16)) ----
    #pragma unroll
    for (int j = 0; j < 6; ++j) {
        bf16x4 pr = *reinterpret_cast<const bf16x4*>(&q_lds[tok * LDH + cseg + j*4]);
        float4 v;
        v.x = xr[j*4+0] + (float)pr[0];
        v.y = xr[j*4+1] + (float)pr[1];
        v.z = xr[j*4+2] + (float)pr[2];
        v.w = xr[j*4+3] + (float)pr[3];
        *reinterpret_cast<float4*>(xmid + gbase + j * 4) = v;
    }
}

// ---------------- kernel 2: LN2 + MLP + residual (in place on xmid) ----------------
#define LDU 104
#define LDC 204   // hidden-chunk stride (192 cols + 12 pad)

__global__ __launch_bounds__(256, 4) void mlp_kernel(
    float* __restrict__ xio, const float* __restrict__ g2v, const float* __restrict__ b2v,
    const float* __restrict__ bm1, const float* __restrict__ bm2,
    const __bf16* __restrict__ ws)
{
    const __bf16* w1t = ws + 36864;
    const __bf16* w2t = ws + 73728;

    __shared__ __align__(16) __bf16 u_lds[64 * LDU];     // 13312 B
    __shared__ __align__(16) __bf16 hid[64 * LDC];       // 26112 B -> total 39424 B

    const int tid = threadIdx.x;
    const int wv = tid >> 6, lane = tid & 63;
    const int c = lane & 15, g = lane >> 4;
    const int mp = wv >> 1, ng = wv & 1;

    const int tok = tid >> 2, cseg = (tid & 3) * 24;
    const long gaddr = ((long)blockIdx.x * 64 + tok) * 96 + cseg;

    const f32x4 fzero = {0.f, 0.f, 0.f, 0.f};

    // ---- LN2 -> u_lds ----
    {
        float xr[24];
        #pragma unroll
        for (int j = 0; j < 6; ++j) {
            float4 v = *reinterpret_cast<const float4*>(xio + gaddr + j * 4);
            xr[j*4+0] = v.x; xr[j*4+1] = v.y; xr[j*4+2] = v.z; xr[j*4+3] = v.w;
        }
        float s = 0.f;
        #pragma unroll
        for (int j = 0; j < 24; ++j) s += xr[j];
        s += __shfl_xor(s, 1); s += __shfl_xor(s, 2);
        float mu = s * (1.0f / 96.0f);
        float vs = 0.f;
        #pragma unroll
        for (int j = 0; j < 24; ++j) { float d = xr[j] - mu; vs += d * d; }
        vs += __shfl_xor(vs, 1); vs += __shfl_xor(vs, 2);
        float rstd = rsqrtf(vs * (1.0f / 96.0f) + 1e-5f);
        #pragma unroll
        for (int j = 0; j < 6; ++j) {
            f32x4 gv = *reinterpret_cast<const f32x4*>(g2v + cseg + j * 4);
            f32x4 bv = *reinterpret_cast<const f32x4*>(b2v + cseg + j * 4);
            bf16x4 o;
            #pragma unroll
            for (int r = 0; r < 4; ++r) o[r] = (__bf16)((xr[j*4+r] - mu) * rstd * gv[r] + bv[r]);
            *reinterpret_cast<bf16x4*>(&u_lds[tok * LDU + cseg + j*4]) = o;
        }
    }
    __syncthreads();  // bar1

    // ---- MLP: 2 chunks of 192 hidden ----
    f32x4 accB[2][3];
    #pragma unroll
    for (int mi = 0; mi < 2; ++mi)
        #pragma unroll
        for (int nl = 0; nl < 3; ++nl) accB[mi][nl] = fzero;

    #pragma unroll
    for (int ch = 0; ch < 2; ++ch) {
        // GEMM A (swapped): A=w1 rows (tiles ch*12+wv*3+i), B=token tiles tt -> hid[tok][hidcol] (+gelu)
        f32x4 accA[3][4];
        #pragma unroll
        for (int i = 0; i < 3; ++i)
            #pragma unroll
            for (int tt = 0; tt < 4; ++tt) accA[i][tt] = fzero;
        #pragma unroll
        for (int kc = 0; kc < 3; ++kc) {
            bf16x8 bU[4];
            #pragma unroll
            for (int tt = 0; tt < 4; ++tt)
                bU[tt] = *reinterpret_cast<const bf16x8*>(&u_lds[(tt*16 + c) * LDU + kc*32 + g*8]);
            #pragma unroll
            for (int i = 0; i < 3; ++i) {
                bf16x8 aW = *reinterpret_cast<const bf16x8*>(&w1t[((ch*12 + wv*3 + i)*16 + c) * 96 + kc*32 + g*8]);
                #pragma unroll
                for (int tt = 0; tt < 4; ++tt)
                    accA[i][tt] = MFMA(aW, bU[tt], accA[i][tt]);
            }
        }
        #pragma unroll
        for (int i = 0; i < 3; ++i) {
            f32x4 bb = *reinterpret_cast<const f32x4*>(&bm1[ch*192 + (wv*3 + i)*16 + 4*g]);
            #pragma unroll
            for (int tt = 0; tt < 4; ++tt) {
                bf16x4 o;
                #pragma unroll
                for (int r = 0; r < 4; ++r) o[r] = (__bf16)gelu_f(accA[i][tt][r] + bb[r]);
                *reinterpret_cast<bf16x4*>(&hid[(tt*16 + c) * LDC + (wv*3 + i)*16 + 4*g]) = o;
            }
        }
        __syncthreads();  // hid ready

        // GEMM B (swapped, R2 split): wave (mp,ng): A=w2 rows ng*3+nl, B=token tiles mp*2+mi. K=192
        #pragma unroll
        for (int kc = 0; kc < 6; ++kc) {
            bf16x8 bHd[2];
            #pragma unroll
            for (int mi = 0; mi < 2; ++mi)
                bHd[mi] = *reinterpret_cast<const bf16x8*>(&hid[((mp*2+mi)*16 + c) * LDC + kc*32 + g*8]);
            #pragma unroll
            for (int nl = 0; nl < 3; ++nl) {
                bf16x8 aW = *reinterpret_cast<const bf16x8*>(&w2t[((ng*3+nl)*16 + c) * 384 + ch*192 + kc*32 + g*8]);
                #pragma unroll
                for (int mi = 0; mi < 2; ++mi)
                    accB[mi][nl] = MFMA(aW, bHd[mi], accB[mi][nl]);
            }
        }
        if (ch == 0) __syncthreads();  // protect hid overwrite by next chunk
    }

    // ---- epilogue (vector): value(tok=(mp*2+mi)*16+c, outcol=(ng*3+nl)*16+4g+r) -> u_lds ----
    #pragma unroll
    for (int nl = 0; nl < 3; ++nl) {
        f32x4 bb = *reinterpret_cast<const f32x4*>(&bm2[(ng*3+nl)*16 + 4*g]);
        #pragma unroll
        for (int mi = 0; mi < 2; ++mi) {
            bf16x4 o;
            #pragma unroll
            for (int r = 0; r < 4; ++r) o[r] = (__bf16)(accB[mi][nl][r] + bb[r]);
            *reinterpret_cast<bf16x4*>(&u_lds[((mp*2+mi)*16 + c) * LDU + (ng*3+nl)*16 + 4*g]) = o;
        }
    }
    __syncthreads();  // cross-wave epilogue exchange

    // ---- residual: out = x + mlp (re-read x; L2/L3-resident) ----
    #pragma unroll
    for (int j = 0; j < 6; ++j) {
        float4 xv = *reinterpret_cast<const float4*>(xio + gaddr + j * 4);
        bf16x4 mo = *reinterpret_cast<const bf16x4*>(&u_lds[tok * LDU + cseg + j*4]);
        float4 v;
        v.x = xv.x + (float)mo[0];
        v.y = xv.y + (float)mo[1];
        v.z = xv.z + (float)mo[2];
        v.w = xv.w + (float)mo[3];
        *reinterpret_cast<float4*>(xio + gaddr + j * 4) = v;
    }
}

extern "C" void kernel_launch(void* const* d_in, const int* in_sizes, int n_in,
                              void* d_out, int out_size, void* d_ws, size_t ws_size,
                              hipStream_t stream) {
    (void)in_sizes; (void)n_in; (void)out_size; (void)ws_size;
    const float* x   = (const float*)d_in[0];
    const float* g1  = (const float*)d_in[1];
    const float* b1  = (const float*)d_in[2];
    const float* wq  = (const float*)d_in[3];
    const float* bq  = (const float*)d_in[4];
    const float* wkv = (const float*)d_in[5];
    const float* bkv = (const float*)d_in[6];
    const float* wp  = (const float*)d_in[7];
    const float* bp  = (const float*)d_in[8];
    const float* g2  = (const float*)d_in[9];
    const float* b2  = (const float*)d_in[10];
    const float* w1  = (const float*)d_in[11];
    const float* bm1 = (const float*)d_in[12];
    const float* w2  = (const float*)d_in[13];
    const float* bm2 = (const float*)d_in[14];
    float* out = (float*)d_out;
    __bf16* ws = (__bf16*)d_ws;

    prep_weights<<<432, 256, 0, stream>>>(wq, wkv, wp, w1, w2, ws);
    attn_kernel<<<9216, 256, 0, stream>>>(x, g1, b1, bq, bkv, bp, ws, out);
    mlp_kernel<<<9216, 256, 0, stream>>>(out, g2, b2, bm1, bm2, ws);
}

// Round 7
// 498.258 us; speedup vs baseline: 1.6908x; 1.1541x over previous
//
#include <hip/hip_runtime.h>

typedef __bf16 bf16x8 __attribute__((ext_vector_type(8)));
typedef __bf16 bf16x4 __attribute__((ext_vector_type(4)));
typedef float f32x4 __attribute__((ext_vector_type(4)));

#define MFMA(a,b,c) __builtin_amdgcn_mfma_f32_16x16x32_bf16(a, b, c, 0, 0, 0)

__device__ __forceinline__ float gelu_f(float t) {
    float t2 = t * t;
    float m = t * __builtin_fmaf(-0.07135481627f, t2, -1.5957691216f); // -2z
    float e = __expf(m);
    return t * __builtin_amdgcn_rcpf(1.0f + e);
}

__device__ __forceinline__ bf16x4 shfl_b4(bf16x4 v, int srcLane) {
    union { bf16x4 b; int i[2]; } u; u.b = v;
    u.i[0] = __shfl(u.i[0], srcLane);
    u.i[1] = __shfl(u.i[1], srcLane);
    return u.b;
}
// Build B-fragment bf16x8 for k-cols m*32 + g*8 + e (e=0..7), token=c, from packs
// pk[nt] = vals at cols nt*16+4*g'+r (tok=c). Source lanes c+32*(g&1)(+16).
__device__ __forceinline__ bf16x8 frag_from_packs(const bf16x4* pk, int m, int g, int c) {
    int l_lo = c + 32 * (g & 1);
    int l_hi = l_lo + 16;
    bf16x4 a0 = shfl_b4(pk[2*m],   l_lo);
    bf16x4 a1 = shfl_b4(pk[2*m+1], l_lo);
    bf16x4 b0 = shfl_b4(pk[2*m],   l_hi);
    bf16x4 b1 = shfl_b4(pk[2*m+1], l_hi);
    bool sel = ((g >> 1) & 1);
    bf16x4 lo = sel ? a1 : a0;
    bf16x4 hi = sel ? b1 : b0;
    bf16x8 r;
    #pragma unroll
    for (int i = 0; i < 4; ++i) { r[i] = lo[i]; r[i+4] = hi[i]; }
    return r;
}

// ---------------- kernel 0: weight prep (transpose + bf16, fold qk scale) ----------------
__global__ void prep_weights(const float* __restrict__ wq, const float* __restrict__ wkv,
                             const float* __restrict__ wp, const float* __restrict__ w1,
                             const float* __restrict__ w2, __bf16* __restrict__ ws) {
    int i = blockIdx.x * 256 + threadIdx.x;
    const float scale = 0.17677669529663687f; // 1/sqrt(32)
    if (i < 9216) {                       // wqt[n][k] = wq[k][n]*scale
        int n = i / 96, k = i % 96;
        ws[i] = (__bf16)(wq[k * 96 + n] * scale);
    } else if (i < 27648) {               // wkvt[n][k], n in [0,192)
        int j = i - 9216; int n = j / 96, k = j % 96;
        ws[i] = (__bf16)(wkv[k * 192 + n]);
    } else if (i < 36864) {               // wpt[n][k]
        int j = i - 27648; int n = j / 96, k = j % 96;
        ws[i] = (__bf16)(wp[k * 96 + n]);
    } else if (i < 73728) {               // w1t[n][k], n in [0,384), k in [0,96)
        int j = i - 36864; int n = j / 96, k = j % 96;
        ws[i] = (__bf16)(w1[k * 384 + n]);
    } else if (i < 110592) {              // w2t[n][k], n in [0,96), k in [0,384)
        int j = i - 73728; int n = j / 384, k = j % 384;
        ws[i] = (__bf16)(w2[k * 96 + n]);
    }
}

// ---------------- kernel 1: LN1 + window attention + proj + residual ----------------
#define LDH 104   // 96 + pad
#define LDV 72

#define AOFF_H   0
#define AOFF_Q   6656
#define AOFF_K   13312
#define AOFF_VT  19968
#define ASMEM    26880      // bf16 elems -> 53760 B -> 3 blocks/CU

__global__ __launch_bounds__(256, 2) void attn_kernel(
    const float* __restrict__ x, const float* __restrict__ g1v, const float* __restrict__ b1v,
    const float* __restrict__ bq, const float* __restrict__ bkv, const float* __restrict__ bp,
    const __bf16* __restrict__ ws, float* __restrict__ xmid)
{
    const __bf16* wqt  = ws;
    const __bf16* wkvt = ws + 9216;
    const __bf16* wpt  = ws + 27648;

    __shared__ __align__(16) __bf16 smem[ASMEM];
    __bf16* h_lds  = smem + AOFF_H;   // LN1 out -> attn out
    __bf16* q_lds  = smem + AOFF_Q;   // q -> proj out
    __bf16* k_lds  = smem + AOFF_K;
    __bf16* vt_lds = smem + AOFF_VT;  // v transposed [vcol][tok]

    const int tid = threadIdx.x;
    const int wv = tid >> 6, lane = tid & 63;
    const int c = lane & 15, g = lane >> 4;

    const int wid = blockIdx.x;
    const int wdI = wid / 576, rem = wid % 576, whI = rem / 24, wwI = rem % 24;
    const int tok = tid >> 2, cseg = (tid & 3) * 24;
    const int dz = tok >> 4, hy = (tok >> 2) & 3, wx = tok & 3;
    const long gbase = (((long)(wdI * 4 + dz) * 96 + (whI * 4 + hy)) * 96 + (wwI * 4 + wx)) * 96 + cseg;

    const f32x4 fzero = {0.f, 0.f, 0.f, 0.f};

    // ---- phase 0: load x window, LN1 -> h_lds ----
    float xr[24];
    #pragma unroll
    for (int j = 0; j < 6; ++j) {
        float4 v = *reinterpret_cast<const float4*>(x + gbase + j * 4);
        xr[j*4+0] = v.x; xr[j*4+1] = v.y; xr[j*4+2] = v.z; xr[j*4+3] = v.w;
    }
    {
        float s = 0.f;
        #pragma unroll
        for (int j = 0; j < 24; ++j) s += xr[j];
        s += __shfl_xor(s, 1); s += __shfl_xor(s, 2);
        float mu = s * (1.0f / 96.0f);
        float vs = 0.f;
        #pragma unroll
        for (int j = 0; j < 24; ++j) { float d = xr[j] - mu; vs += d * d; }
        vs += __shfl_xor(vs, 1); vs += __shfl_xor(vs, 2);
        float rstd = rsqrtf(vs * (1.0f / 96.0f) + 1e-5f);
        #pragma unroll
        for (int j = 0; j < 6; ++j) {
            f32x4 gv = *reinterpret_cast<const f32x4*>(g1v + cseg + j * 4);
            f32x4 bv = *reinterpret_cast<const f32x4*>(b1v + cseg + j * 4);
            bf16x4 o;
            #pragma unroll
            for (int r = 0; r < 4; ++r) o[r] = (__bf16)((xr[j*4+r] - mu) * rstd * gv[r] + bv[r]);
            *reinterpret_cast<bf16x4*>(&h_lds[tok * LDH + cseg + j*4]) = o;
        }
    }
    __syncthreads();  // bar1

    // ---- phase 1: QKV projections ----
    // q (all waves, swapped: A=wq rows, B=own token-tile) -> q_lds[tok][qcol]
    {
        bf16x8 bH[3];
        #pragma unroll
        for (int kc = 0; kc < 3; ++kc)
            bH[kc] = *reinterpret_cast<const bf16x8*>(&h_lds[(wv*16 + c) * LDH + kc*32 + g*8]);
        f32x4 aq[6];
        #pragma unroll
        for (int nt = 0; nt < 6; ++nt) aq[nt] = fzero;
        #pragma unroll
        for (int nt = 0; nt < 6; ++nt)
            #pragma unroll
            for (int kc = 0; kc < 3; ++kc) {
                bf16x8 aW = *reinterpret_cast<const bf16x8*>(&wqt[(nt*16 + c) * 96 + kc*32 + g*8]);
                aq[nt] = MFMA(aW, bH[kc], aq[nt]);
            }
        #pragma unroll
        for (int nt = 0; nt < 6; ++nt) {
            f32x4 bb = *reinterpret_cast<const f32x4*>(&bq[nt*16 + 4*g]);
            bf16x4 o;
            #pragma unroll
            for (int r = 0; r < 4; ++r) o[r] = (__bf16)(aq[nt][r] + bb[r] * 0.17677669529663687f);
            *reinterpret_cast<bf16x4*>(&q_lds[(wv*16 + c) * LDH + nt*16 + 4*g]) = o;
        }
    }
    if (wv < 2) {
        // k (swapped): waves 0,1 cover token-tiles {2wv, 2wv+1} -> k_lds[tok][kcol]
        #pragma unroll
        for (int t2 = 0; t2 < 2; ++t2) {
            int tt = wv*2 + t2;
            bf16x8 bH[3];
            #pragma unroll
            for (int kc = 0; kc < 3; ++kc)
                bH[kc] = *reinterpret_cast<const bf16x8*>(&h_lds[(tt*16 + c) * LDH + kc*32 + g*8]);
            f32x4 ak[6];
            #pragma unroll
            for (int nt = 0; nt < 6; ++nt) ak[nt] = fzero;
            #pragma unroll
            for (int nt = 0; nt < 6; ++nt)
                #pragma unroll
                for (int kc = 0; kc < 3; ++kc) {
                    bf16x8 aW = *reinterpret_cast<const bf16x8*>(&wkvt[(nt*16 + c) * 96 + kc*32 + g*8]);
                    ak[nt] = MFMA(aW, bH[kc], ak[nt]);
                }
            #pragma unroll
            for (int nt = 0; nt < 6; ++nt) {
                f32x4 bb = *reinterpret_cast<const f32x4*>(&bkv[nt*16 + 4*g]);
                bf16x4 o;
                #pragma unroll
                for (int r = 0; r < 4; ++r) o[r] = (__bf16)(ak[nt][r] + bb[r]);
                *reinterpret_cast<bf16x4*>(&k_lds[(tt*16 + c) * LDH + nt*16 + 4*g]) = o;
            }
        }
    } else {
        // v (unswapped: A=token rows, B=wkv v-rows) -> vt_lds[vcol][tok]
        f32x4 av[4][3];
        #pragma unroll
        for (int m = 0; m < 4; ++m)
            #pragma unroll
            for (int nl = 0; nl < 3; ++nl) av[m][nl] = fzero;
        #pragma unroll
        for (int kc = 0; kc < 3; ++kc) {
            bf16x8 aH[4];
            #pragma unroll
            for (int m = 0; m < 4; ++m)
                aH[m] = *reinterpret_cast<const bf16x8*>(&h_lds[(m*16 + c) * LDH + kc*32 + g*8]);
            #pragma unroll
            for (int nl = 0; nl < 3; ++nl) {
                int nv = (wv - 2) * 3 + nl;
                bf16x8 bW = *reinterpret_cast<const bf16x8*>(&wkvt[(96 + nv*16 + c) * 96 + kc*32 + g*8]);
                #pragma unroll
                for (int m = 0; m < 4; ++m)
                    av[m][nl] = MFMA(aH[m], bW, av[m][nl]);
            }
        }
        #pragma unroll
        for (int nl = 0; nl < 3; ++nl) {
            int nv = (wv - 2) * 3 + nl;
            float bias = bkv[96 + nv*16 + c];
            #pragma unroll
            for (int m = 0; m < 4; ++m) {
                bf16x4 o;
                #pragma unroll
                for (int r = 0; r < 4; ++r) o[r] = (__bf16)(av[m][nl][r] + bias);
                *reinterpret_cast<bf16x4*>(&vt_lds[(nv*16 + c) * LDV + m*16 + 4*g]) = o;
            }
        }
    }
    __syncthreads();  // bar2

    // ---- phase 2: attention (wave wv owns query tile wv); P in registers ----
    #pragma unroll
    for (int h = 0; h < 3; ++h) {
        // QK^T swapped: A=key tiles, B=own q tile. sacc[nt][r] = S[key=nt*16+4g+r][qtok=c]
        f32x4 sacc[4];
        bf16x8 bQ = *reinterpret_cast<const bf16x8*>(&q_lds[(wv*16 + c) * LDH + h*32 + g*8]);
        #pragma unroll
        for (int nt = 0; nt < 4; ++nt) {
            bf16x8 aK = *reinterpret_cast<const bf16x8*>(&k_lds[(nt*16 + c) * LDH + h*32 + g*8]);
            sacc[nt] = fzero;
            sacc[nt] = MFMA(aK, bQ, sacc[nt]);
        }
        // softmax over keys (16 in-lane + cross-g shfls)
        float mx = sacc[0][0];
        #pragma unroll
        for (int nt = 0; nt < 4; ++nt)
            #pragma unroll
            for (int r = 0; r < 4; ++r) mx = fmaxf(mx, sacc[nt][r]);
        mx = fmaxf(mx, __shfl_xor(mx, 16));
        mx = fmaxf(mx, __shfl_xor(mx, 32));
        float p[4][4]; float se = 0.f;
        #pragma unroll
        for (int nt = 0; nt < 4; ++nt)
            #pragma unroll
            for (int r = 0; r < 4; ++r) { p[nt][r] = __expf(sacc[nt][r] - mx); se += p[nt][r]; }
        se += __shfl_xor(se, 16);
        se += __shfl_xor(se, 32);
        float rsinv = __builtin_amdgcn_rcpf(se);
        bf16x4 pp[4];
        #pragma unroll
        for (int nt = 0; nt < 4; ++nt)
            #pragma unroll
            for (int r = 0; r < 4; ++r) pp[nt][r] = (__bf16)p[nt][r];

        // PV swapped: A=vt rows (vcols), B=P fragments built by lane shuffles
        f32x4 oacc[2];
        oacc[0] = fzero;
        oacc[1] = fzero;
        #pragma unroll
        for (int kc = 0; kc < 2; ++kc) {
            bf16x8 bP = frag_from_packs(pp, kc, g, c);
            #pragma unroll
            for (int n2 = 0; n2 < 2; ++n2) {
                bf16x8 aV = *reinterpret_cast<const bf16x8*>(&vt_lds[(h*32 + n2*16 + c) * LDV + kc*32 + g*8]);
                oacc[n2] = MFMA(aV, bP, oacc[n2]);
            }
        }
        #pragma unroll
        for (int n2 = 0; n2 < 2; ++n2) {
            bf16x4 o;
            #pragma unroll
            for (int r = 0; r < 4; ++r) o[r] = (__bf16)(oacc[n2][r] * rsinv);
            *reinterpret_cast<bf16x4*>(&h_lds[(wv*16 + c) * LDH + h*32 + n2*16 + 4*g]) = o;
        }
    }

    // ---- phase 3: proj (swapped; own-wave rows only, no barrier needed) ----
    {
        bf16x8 bA[3];
        #pragma unroll
        for (int kc = 0; kc < 3; ++kc)
            bA[kc] = *reinterpret_cast<const bf16x8*>(&h_lds[(wv*16 + c) * LDH + kc*32 + g*8]);
        f32x4 ap[6];
        #pragma unroll
        for (int nt = 0; nt < 6; ++nt) ap[nt] = fzero;
        #pragma unroll
        for (int nt = 0; nt < 6; ++nt)
            #pragma unroll
            for (int kc = 0; kc < 3; ++kc) {
                bf16x8 aW = *reinterpret_cast<const bf16x8*>(&wpt[(nt*16 + c) * 96 + kc*32 + g*8]);
                ap[nt] = MFMA(aW, bA[kc], ap[nt]);
            }
        #pragma unroll
        for (int nt = 0; nt < 6; ++nt) {
            f32x4 bb = *reinterpret_cast<const f32x4*>(&bp[nt*16 + 4*g]);
            bf16x4 o;
            #pragma unroll
            for (int r = 0; r < 4; ++r) o[r] = (__bf16)(ap[nt][r] + bb[r]);
            *reinterpret_cast<bf16x4*>(&q_lds[(wv*16 + c) * LDH + nt*16 + 4*g]) = o;
        }
    }

    // ---- phase 4: residual store (tok rows are own-wave rows) ----
    #pragma unroll
    for (int j = 0; j < 6; ++j) {
        bf16x4 pr = *reinterpret_cast<const bf16x4*>(&q_lds[tok * LDH + cseg + j*4]);
        float4 v;
        v.x = xr[j*4+0] + (float)pr[0];
        v.y = xr[j*4+1] + (float)pr[1];
        v.z = xr[j*4+2] + (float)pr[2];
        v.w = xr[j*4+3] + (float)pr[3];
        *reinterpret_cast<float4*>(xmid + gbase + j * 4) = v;
    }
}

// ---------------- kernel 2: LN2 + MLP + residual (384 threads, chunk=96) ----------------
#define LDU 104
#define LDC2 104

__global__ __launch_bounds__(384, 4) void mlp_kernel(
    float* __restrict__ xio, const float* __restrict__ g2v, const float* __restrict__ b2v,
    const float* __restrict__ bm1, const float* __restrict__ bm2,
    const __bf16* __restrict__ ws)
{
    const __bf16* w1t = ws + 36864;
    const __bf16* w2t = ws + 73728;

    __shared__ __align__(16) __bf16 u_lds[64 * LDU];     // 13312 B
    __shared__ __align__(16) __bf16 hid[64 * LDC2];      // 13312 B -> total 26624 B -> 5 blk/CU (wave cap)

    const int tid = threadIdx.x;
    const int wv = tid >> 6, lane = tid & 63;     // wv in [0,6)
    const int c = lane & 15, g = lane >> 4;

    const int tok = tid >> 2, cseg = (tid & 3) * 24;   // valid for tid<256
    const long gaddr = ((long)blockIdx.x * 64 + tok) * 96 + cseg;

    const f32x4 fzero = {0.f, 0.f, 0.f, 0.f};

    // ---- LN2 -> u_lds (threads 0..255) ----
    if (tid < 256) {
        float xr[24];
        #pragma unroll
        for (int j = 0; j < 6; ++j) {
            float4 v = *reinterpret_cast<const float4*>(xio + gaddr + j * 4);
            xr[j*4+0] = v.x; xr[j*4+1] = v.y; xr[j*4+2] = v.z; xr[j*4+3] = v.w;
        }
        float s = 0.f;
        #pragma unroll
        for (int j = 0; j < 24; ++j) s += xr[j];
        s += __shfl_xor(s, 1); s += __shfl_xor(s, 2);
        float mu = s * (1.0f / 96.0f);
        float vs = 0.f;
        #pragma unroll
        for (int j = 0; j < 24; ++j) { float d = xr[j] - mu; vs += d * d; }
        vs += __shfl_xor(vs, 1); vs += __shfl_xor(vs, 2);
        float rstd = rsqrtf(vs * (1.0f / 96.0f) + 1e-5f);
        #pragma unroll
        for (int j = 0; j < 6; ++j) {
            f32x4 gv = *reinterpret_cast<const f32x4*>(g2v + cseg + j * 4);
            f32x4 bv = *reinterpret_cast<const f32x4*>(b2v + cseg + j * 4);
            bf16x4 o;
            #pragma unroll
            for (int r = 0; r < 4; ++r) o[r] = (__bf16)((xr[j*4+r] - mu) * rstd * gv[r] + bv[r]);
            *reinterpret_cast<bf16x4*>(&u_lds[tok * LDU + cseg + j*4]) = o;
        }
    }
    __syncthreads();  // bar: u ready

    // ---- MLP: 4 chunks of 96 hidden; wave wv owns hid-tile wv and out-tile wv ----
    f32x4 accB[4];
    #pragma unroll
    for (int tt = 0; tt < 4; ++tt) accB[tt] = fzero;

    #pragma unroll
    for (int ch = 0; ch < 4; ++ch) {
        // GEMM A: hid-tile (ch*6+wv): A = w1 rows, B = token tiles
        f32x4 accA[4];
        #pragma unroll
        for (int tt = 0; tt < 4; ++tt) accA[tt] = fzero;
        #pragma unroll
        for (int kc = 0; kc < 3; ++kc) {
            bf16x8 aW = *reinterpret_cast<const bf16x8*>(&w1t[((ch*6 + wv)*16 + c) * 96 + kc*32 + g*8]);
            #pragma unroll
            for (int tt = 0; tt < 4; ++tt) {
                bf16x8 bU = *reinterpret_cast<const bf16x8*>(&u_lds[(tt*16 + c) * LDU + kc*32 + g*8]);
                accA[tt] = MFMA(aW, bU, accA[tt]);
            }
        }
        {
            f32x4 bb = *reinterpret_cast<const f32x4*>(&bm1[(ch*6 + wv)*16 + 4*g]);
            #pragma unroll
            for (int tt = 0; tt < 4; ++tt) {
                bf16x4 o;
                #pragma unroll
                for (int r = 0; r < 4; ++r) o[r] = (__bf16)gelu_f(accA[tt][r] + bb[r]);
                *reinterpret_cast<bf16x4*>(&hid[(tt*16 + c) * LDC2 + wv*16 + 4*g]) = o;
            }
        }
        __syncthreads();  // hid ready

        // GEMM B: out-tile wv: A = w2 rows (out cols), B = token tiles. K = 96 chunk
        #pragma unroll
        for (int kc = 0; kc < 3; ++kc) {
            bf16x8 aW2 = *reinterpret_cast<const bf16x8*>(&w2t[(wv*16 + c) * 384 + ch*96 + kc*32 + g*8]);
            #pragma unroll
            for (int tt = 0; tt < 4; ++tt) {
                bf16x8 bHd = *reinterpret_cast<const bf16x8*>(&hid[(tt*16 + c) * LDC2 + kc*32 + g*8]);
                accB[tt] = MFMA(aW2, bHd, accB[tt]);
            }
        }
        if (ch < 3) __syncthreads();  // protect hid overwrite by next chunk
    }

    // ---- epilogue: value(tok=tt*16+c, outcol=wv*16+4g+r) -> u_lds (u is dead) ----
    {
        f32x4 bb = *reinterpret_cast<const f32x4*>(&bm2[wv*16 + 4*g]);
        #pragma unroll
        for (int tt = 0; tt < 4; ++tt) {
            bf16x4 o;
            #pragma unroll
            for (int r = 0; r < 4; ++r) o[r] = (__bf16)(accB[tt][r] + bb[r]);
            *reinterpret_cast<bf16x4*>(&u_lds[(tt*16 + c) * LDU + wv*16 + 4*g]) = o;
        }
    }
    __syncthreads();  // cross-wave epilogue exchange

    // ---- residual: out = x + mlp (threads 0..255; re-read x, L2-resident) ----
    if (tid < 256) {
        #pragma unroll
        for (int j = 0; j < 6; ++j) {
            float4 xv = *reinterpret_cast<const float4*>(xio + gaddr + j * 4);
            bf16x4 mo = *reinterpret_cast<const bf16x4*>(&u_lds[tok * LDU + cseg + j*4]);
            float4 v;
            v.x = xv.x + (float)mo[0];
            v.y = xv.y + (float)mo[1];
            v.z = xv.z + (float)mo[2];
            v.w = xv.w + (float)mo[3];
            *reinterpret_cast<float4*>(xio + gaddr + j * 4) = v;
        }
    }
}

extern "C" void kernel_launch(void* const* d_in, const int* in_sizes, int n_in,
                              void* d_out, int out_size, void* d_ws, size_t ws_size,
                              hipStream_t stream) {
    (void)in_sizes; (void)n_in; (void)out_size; (void)ws_size;
    const float* x   = (const float*)d_in[0];
    const float* g1  = (const float*)d_in[1];
    const float* b1  = (const float*)d_in[2];
    const float* wq  = (const float*)d_in[3];
    const float* bq  = (const float*)d_in[4];
    const float* wkv = (const float*)d_in[5];
    const float* bkv = (const float*)d_in[6];
    const float* wp  = (const float*)d_in[7];
    const float* bp  = (const float*)d_in[8];
    const float* g2  = (const float*)d_in[9];
    const float* b2  = (const float*)d_in[10];
    const float* w1  = (const float*)d_in[11];
    const float* bm1 = (const float*)d_in[12];
    const float* w2  = (const float*)d_in[13];
    const float* bm2 = (const float*)d_in[14];
    float* out = (float*)d_out;
    __bf16* ws = (__bf16*)d_ws;

    prep_weights<<<432, 256, 0, stream>>>(wq, wkv, wp, w1, w2, ws);
    attn_kernel<<<9216, 256, 0, stream>>>(x, g1, b1, bq, bkv, bp, ws, out);
    mlp_kernel<<<9216, 384, 0, stream>>>(out, g2, b2, bm1, bm2, ws);
}